// Round 8
// baseline (1365.143 us; speedup 1.0000x reference)
//
#include <hip/hip_runtime.h>
#include <hip/hip_cooperative_groups.h>
#include <hip/hip_bf16.h>
#include <math.h>

#define D_MODEL 2048
#define D_INNER 4096
#define D_STATE 16
#define DT_RANK 128
#define NB      2
#define TT      1024
#define M_TOT   (NB * TT)
#define NC      16                 // scan chunks
#define CL      64                 // chunk length
#define CTC     32                 // conv t-chunk (1024 blocks)

typedef __bf16 bf16x8_t __attribute__((ext_vector_type(8)));
typedef float  f32x4_t  __attribute__((ext_vector_type(4)));

// ===========================================================================
// Device stage functions (shared by megakernel and standalone fallback)
// ===========================================================================

// ---- stage: fused cast/zero.  g = 16-byte group index, total 4997120. ----
__device__ __forceinline__ void dev_cast(
    size_t g,
    const float* x,  const float* wi, const float* wo, const float* wx,
    const float* wdt,
    __bf16* x16, __bf16* wi16, __bf16* wo16, __bf16* wx16,
    __bf16* wdt16, __bf16* dbc16, __bf16* out16)
{
    const float* src; __bf16* dst; size_t off;
    if      (g < 524288)  { src = x;   dst = x16;   off = g; }
    else if (g < 2621440) { src = wi;  dst = wi16;  off = g - 524288; }
    else if (g < 3670016) { src = wo;  dst = wo16;  off = g - 2621440; }
    else if (g < 3801088) { off = g - 3670016; dst = wx16;
                            src = (g < 3751936) ? wx : nullptr; }
    else if (g < 3866624) { src = wdt; dst = wdt16; off = g - 3801088; }
    else if (g < 3948544) { src = nullptr; dst = dbc16; off = g - 3866624; }
    else                  { src = nullptr; dst = out16; off = g - 3948544; }

    bf16x8_t v;
    if (src) {
        const float4 f0 = ((const float4*)src)[2 * off];
        const float4 f1 = ((const float4*)src)[2 * off + 1];
        v[0] = (__bf16)f0.x; v[1] = (__bf16)f0.y; v[2] = (__bf16)f0.z; v[3] = (__bf16)f0.w;
        v[4] = (__bf16)f1.x; v[5] = (__bf16)f1.y; v[6] = (__bf16)f1.z; v[7] = (__bf16)f1.w;
    } else {
        v = (bf16x8_t)(__bf16)0.f;
    }
    ((bf16x8_t*)dst)[off] = v;
}

// ---- stage: bf16 MFMA GEMM 128x128 tile, m97 structure ----
template <int EPI, int KSTEP, typename OutT>
__device__ __forceinline__ void dev_gemm(
    const __bf16* __restrict__ A, int lda,
    const __bf16* __restrict__ W, int ldw,
    OutT* __restrict__ C, int ldc,
    int Kloop, int Nmax, const float* __restrict__ bias,
    int bx, int by, int bz, __bf16* As, __bf16* Bs, int tid)
{
    const int wave = tid >> 6;
    const int lane = tid & 63;
    const int m0 = by * 128;
    const int n0 = bx * 128;
    const int mw = (wave >> 1) * 64;
    const int nw = (wave & 1) * 64;
    const int koff = bz * Kloop;

    f32x4_t acc[4][4] = {};

    const int g0 = wave * 2;
    const int rA = g0 * 16 + (lane >> 2);
    const int kk = (lane & 3) * 8;

    const __bf16* gA0 = A + (size_t)(m0 + rA) * lda + kk + koff;
    const __bf16* gA1 = gA0 + (size_t)16 * lda;
    const __bf16* gB0 = W + (size_t)(n0 + rA) * ldw + kk + koff;
    const __bf16* gB1 = gB0 + (size_t)16 * ldw;

    __bf16* lA0 = As + (size_t)g0 * 512;
    __bf16* lA1 = As + (size_t)(g0 + 1) * 512;
    __bf16* lB0 = Bs + (size_t)g0 * 512;
    __bf16* lB1 = Bs + (size_t)(g0 + 1) * 512;

    const int fr = lane & 15;
    const int fk = (lane >> 4) * 8;

    for (int k0 = 0; k0 < Kloop; k0 += KSTEP) {
#pragma unroll
        for (int p = 0; p < KSTEP / 32; p++) {
            const int kp = k0 + p * 32;
            const int lp = p * 4096;
            __builtin_amdgcn_global_load_lds(
                (const __attribute__((address_space(1))) void*)(gA0 + kp),
                (__attribute__((address_space(3))) void*)(lA0 + lp), 16, 0, 0);
            __builtin_amdgcn_global_load_lds(
                (const __attribute__((address_space(1))) void*)(gA1 + kp),
                (__attribute__((address_space(3))) void*)(lA1 + lp), 16, 0, 0);
            __builtin_amdgcn_global_load_lds(
                (const __attribute__((address_space(1))) void*)(gB0 + kp),
                (__attribute__((address_space(3))) void*)(lB0 + lp), 16, 0, 0);
            __builtin_amdgcn_global_load_lds(
                (const __attribute__((address_space(1))) void*)(gB1 + kp),
                (__attribute__((address_space(3))) void*)(lB1 + lp), 16, 0, 0);
        }
        __syncthreads();

#pragma unroll
        for (int p = 0; p < KSTEP / 32; p++) {
            const int lp = p * 4096;
            bf16x8_t av[4], bv[4];
#pragma unroll
            for (int mt = 0; mt < 4; mt++)
                av[mt] = *(const bf16x8_t*)&As[lp + (mw + mt * 16 + fr) * 32 + fk];
#pragma unroll
            for (int nt = 0; nt < 4; nt++)
                bv[nt] = *(const bf16x8_t*)&Bs[lp + (nw + nt * 16 + fr) * 32 + fk];

#pragma unroll
            for (int mt = 0; mt < 4; mt++)
#pragma unroll
                for (int nt = 0; nt < 4; nt++)
                    acc[mt][nt] = __builtin_amdgcn_mfma_f32_16x16x32_bf16(
                        av[mt], bv[nt], acc[mt][nt], 0, 0, 0);
        }
        __syncthreads();
    }

    // C/D layout: col = lane&15, row = (lane>>4)*4 + reg
    const int cn = n0 + nw + (lane & 15);
    const int rb = m0 + mw + (lane >> 4) * 4;
#pragma unroll
    for (int mt = 0; mt < 4; mt++)
#pragma unroll
        for (int nt = 0; nt < 4; nt++) {
            const int n = cn + nt * 16;
            if (n >= Nmax) continue;
#pragma unroll
            for (int r = 0; r < 4; r++) {
                float v = acc[mt][nt][r];
                OutT* p = &C[(size_t)(rb + mt * 16 + r) * ldc + n];
                if (EPI == 1) {
                    v += bias[n];
                    v = (v > 20.f) ? v : log1pf(__expf(v));
                    *p = (OutT)v;
                } else if (EPI == 2) {
                    atomicAdd((float*)p, v);
                } else {
                    *p = (OutT)v;
                }
            }
        }
}

// ---- stage: dt_proj GEMM with inlined fp32->bf16 A staging ----
__device__ __forceinline__ void dev_dt(
    const float* __restrict__ A,      // dbc (ld 160)
    const __bf16* __restrict__ W,     // wdt16 (4096,128)
    __bf16* __restrict__ C,           // delta16 (ld 4096)
    const float* __restrict__ bias,
    int bx, int by, __bf16* As, __bf16* Bs, int tid)
{
    const int wave = tid >> 6;
    const int lane = tid & 63;
    const int m0 = by * 128;
    const int n0 = bx * 128;
    const int mw = (wave >> 1) * 64;
    const int nw = (wave & 1) * 64;

    f32x4_t acc[4][4] = {};

    const int g0 = wave * 2;
    const int rA = g0 * 16 + (lane >> 2);
    const int kk = (lane & 3) * 8;

    const float*  gA0 = A + (size_t)(m0 + rA) * 160 + kk;
    const float*  gA1 = gA0 + (size_t)16 * 160;
    const __bf16* gB0 = W + (size_t)(n0 + rA) * 128 + kk;
    const __bf16* gB1 = gB0 + (size_t)16 * 128;

    __bf16* lA0 = As + (size_t)g0 * 512;
    __bf16* lA1 = As + (size_t)(g0 + 1) * 512;
    __bf16* lB0 = Bs + (size_t)g0 * 512;
    __bf16* lB1 = Bs + (size_t)(g0 + 1) * 512;

    const int fr = lane & 15;
    const int fk = (lane >> 4) * 8;

    for (int k0 = 0; k0 < 128; k0 += 32) {
        const float4 a0 = *(const float4*)(gA0 + k0);
        const float4 a1 = *(const float4*)(gA0 + k0 + 4);
        const float4 a2 = *(const float4*)(gA1 + k0);
        const float4 a3 = *(const float4*)(gA1 + k0 + 4);
        bf16x8_t va, vb;
        va[0] = (__bf16)a0.x; va[1] = (__bf16)a0.y; va[2] = (__bf16)a0.z; va[3] = (__bf16)a0.w;
        va[4] = (__bf16)a1.x; va[5] = (__bf16)a1.y; va[6] = (__bf16)a1.z; va[7] = (__bf16)a1.w;
        vb[0] = (__bf16)a2.x; vb[1] = (__bf16)a2.y; vb[2] = (__bf16)a2.z; vb[3] = (__bf16)a2.w;
        vb[4] = (__bf16)a3.x; vb[5] = (__bf16)a3.y; vb[6] = (__bf16)a3.z; vb[7] = (__bf16)a3.w;
        ((bf16x8_t*)lA0)[lane] = va;
        ((bf16x8_t*)lA1)[lane] = vb;
        __builtin_amdgcn_global_load_lds(
            (const __attribute__((address_space(1))) void*)(gB0 + k0),
            (__attribute__((address_space(3))) void*)lB0, 16, 0, 0);
        __builtin_amdgcn_global_load_lds(
            (const __attribute__((address_space(1))) void*)(gB1 + k0),
            (__attribute__((address_space(3))) void*)lB1, 16, 0, 0);
        __syncthreads();

        bf16x8_t av[4], bv[4];
#pragma unroll
        for (int mt = 0; mt < 4; mt++)
            av[mt] = *(const bf16x8_t*)&As[(mw + mt * 16 + fr) * 32 + fk];
#pragma unroll
        for (int nt = 0; nt < 4; nt++)
            bv[nt] = *(const bf16x8_t*)&Bs[(nw + nt * 16 + fr) * 32 + fk];

#pragma unroll
        for (int mt = 0; mt < 4; mt++)
#pragma unroll
            for (int nt = 0; nt < 4; nt++)
                acc[mt][nt] = __builtin_amdgcn_mfma_f32_16x16x32_bf16(
                    av[mt], bv[nt], acc[mt][nt], 0, 0, 0);
        __syncthreads();
    }

    const int cn = n0 + nw + (lane & 15);
    const int rb = m0 + mw + (lane >> 4) * 4;
#pragma unroll
    for (int mt = 0; mt < 4; mt++)
#pragma unroll
        for (int nt = 0; nt < 4; nt++) {
            const int n = cn + nt * 16;
            const float bs = bias[n];
#pragma unroll
            for (int r = 0; r < 4; r++) {
                float v = acc[mt][nt][r] + bs;
                v = (v > 20.f) ? v : log1pf(__expf(v));
                C[(size_t)(rb + mt * 16 + r) * 4096 + n] = (__bf16)v;
            }
        }
}

// ---- stage: causal depthwise conv(4) + bias + silu; 1024 blocks, CTC=32 ----
__device__ __forceinline__ void dev_conv(
    const __bf16* __restrict__ xz16,
    const float* __restrict__ conv_cache,
    const float* __restrict__ conv_w,
    const float* __restrict__ conv_b,
    __bf16* __restrict__ xs16,
    float* __restrict__ cc_out, int bid, int tid)
{
    const int t0 = (bid & 31) * CTC;
    const int d  = (((bid >> 5) & 15) << 8) + tid;
    const int b  = bid >> 9;

    const float4 w  = *(const float4*)&conv_w[d * 4];
    const float bias = conv_b[d];

    float v[CTC + 3];
    if (t0 == 0) {
        v[0] = conv_cache[(b * D_INNER + d) * 3 + 0];
        v[1] = conv_cache[(b * D_INNER + d) * 3 + 1];
        v[2] = conv_cache[(b * D_INNER + d) * 3 + 2];
    } else {
        v[0] = (float)xz16[(size_t)(b * TT + t0 - 3) * 8192 + d];
        v[1] = (float)xz16[(size_t)(b * TT + t0 - 2) * 8192 + d];
        v[2] = (float)xz16[(size_t)(b * TT + t0 - 1) * 8192 + d];
    }
#pragma unroll
    for (int k = 0; k < CTC; k++)
        v[k + 3] = (float)xz16[(size_t)(b * TT + t0 + k) * 8192 + d];

#pragma unroll
    for (int k = 0; k < CTC; k++) {
        float c = v[k] * w.x + v[k + 1] * w.y + v[k + 2] * w.z + v[k + 3] * w.w + bias;
        float s = c / (1.f + __expf(-c));
        xs16[(size_t)(b * TT + t0 + k) * 4096 + d] = (__bf16)s;
    }

    if (t0 + CTC == TT) {
        cc_out[(b * D_INNER + d) * 3 + 0] = v[CTC];
        cc_out[(b * D_INNER + d) * 3 + 1] = v[CTC + 1];
        cc_out[(b * D_INNER + d) * 3 + 2] = v[CTC + 2];
    }
}

// ---- stage: scan phase A (per-chunk local scan + decay) ----
__device__ __forceinline__ void dev_scanA(
    int idx,
    const __bf16* __restrict__ delta16,
    const float* __restrict__ dbc,
    const __bf16* __restrict__ xs16,
    const float* __restrict__ A_log,
    float* __restrict__ P, float* __restrict__ S)
{
    const int sub = idx & 3;
    const int d   = (idx >> 2) & 4095;
    const int c   = (idx >> 14) & (NC - 1);
    const int b   = idx >> 18;

    const float4 Af = *(const float4*)&A_log[d * 16 + sub * 4];
    const float Ad0 = -__expf(Af.x), Ad1 = -__expf(Af.y);
    const float Ad2 = -__expf(Af.z), Ad3 = -__expf(Af.w);

    const int t0 = c * CL;
    const __bf16* pdelta = delta16 + (size_t)(b * TT + t0) * 4096 + d;
    const __bf16* px     = xs16 + (size_t)(b * TT + t0) * 4096 + d;
    const float*  pB     = dbc + ((size_t)b * TT + t0) * 160 + 128 + sub * 4;

    float h0 = 0.f, h1 = 0.f, h2 = 0.f, h3 = 0.f, sd = 0.f;
#pragma unroll 4
    for (int t = 0; t < CL; t++) {
        const float delta = (float)pdelta[(size_t)t * 4096];
        const float xv    = (float)px[(size_t)t * 4096];
        const float4 Bv   = *(const float4*)&pB[(size_t)t * 160];
        const float dx = delta * xv;
        h0 = __expf(delta * Ad0) * h0 + dx * Bv.x;
        h1 = __expf(delta * Ad1) * h1 + dx * Bv.y;
        h2 = __expf(delta * Ad2) * h2 + dx * Bv.z;
        h3 = __expf(delta * Ad3) * h3 + dx * Bv.w;
        sd += delta;
    }
    const size_t o = ((size_t)(b * NC + c) * 4096 + d) * 16 + sub * 4;
    *(float4*)&P[o] = make_float4(__expf(Ad0 * sd), __expf(Ad1 * sd),
                                  __expf(Ad2 * sd), __expf(Ad3 * sd));
    *(float4*)&S[o] = make_float4(h0, h1, h2, h3);
}

// ---- stage: scan phase C (combine + re-scan, emit gated y, h_out) ----
__device__ __forceinline__ void dev_scanC(
    int idx,
    const __bf16* __restrict__ delta16,
    const __bf16* __restrict__ xz16,
    const float* __restrict__ dbc,
    const __bf16* __restrict__ xs16,
    const float* __restrict__ P, const float* __restrict__ S,
    const float* __restrict__ h_in,
    const float* __restrict__ A_log,
    const float* __restrict__ D_param,
    __bf16* __restrict__ ys16, float* __restrict__ h_out)
{
    const int sub = idx & 3;
    const int d   = (idx >> 2) & 4095;
    const int c   = (idx >> 14) & (NC - 1);   // wave-uniform
    const int b   = idx >> 18;

    const float4 Af = *(const float4*)&A_log[d * 16 + sub * 4];
    const float Ad0 = -__expf(Af.x), Ad1 = -__expf(Af.y);
    const float Ad2 = -__expf(Af.z), Ad3 = -__expf(Af.w);
    const float Dp = D_param[d];

    float4 hf = *(const float4*)&h_in[((size_t)b * 4096 + d) * 16 + sub * 4];
    float h0 = hf.x, h1 = hf.y, h2 = hf.z, h3 = hf.w;
    for (int cc = 0; cc < c; cc++) {
        const size_t o2 = ((size_t)(b * NC + cc) * 4096 + d) * 16 + sub * 4;
        const float4 p = *(const float4*)&P[o2];
        const float4 s = *(const float4*)&S[o2];
        h0 = p.x * h0 + s.x;
        h1 = p.y * h1 + s.y;
        h2 = p.z * h2 + s.z;
        h3 = p.w * h3 + s.w;
    }

    const int t0 = c * CL;
    const __bf16* pdelta = delta16 + (size_t)(b * TT + t0) * 4096 + d;
    const __bf16* pz     = xz16 + (size_t)(b * TT + t0) * 8192 + 4096 + d;
    const __bf16* px     = xs16 + (size_t)(b * TT + t0) * 4096 + d;
    const float*  pB     = dbc + ((size_t)b * TT + t0) * 160 + 128 + sub * 4;
    const float*  pC     = pB + 16;
    __bf16* py = ys16 + (size_t)(b * TT + t0) * 4096 + d;

#pragma unroll 4
    for (int t = 0; t < CL; t++) {
        const float delta = (float)pdelta[(size_t)t * 4096];
        const float xv    = (float)px[(size_t)t * 4096];
        const float4 Bv   = *(const float4*)&pB[(size_t)t * 160];
        const float4 Cv   = *(const float4*)&pC[(size_t)t * 160];
        const float dx = delta * xv;

        h0 = __expf(delta * Ad0) * h0 + dx * Bv.x;
        h1 = __expf(delta * Ad1) * h1 + dx * Bv.y;
        h2 = __expf(delta * Ad2) * h2 + dx * Bv.z;
        h3 = __expf(delta * Ad3) * h3 + dx * Bv.w;

        float y = h0 * Cv.x + h1 * Cv.y + h2 * Cv.z + h3 * Cv.w;
        y += __shfl_xor(y, 1);
        y += __shfl_xor(y, 2);

        if (sub == 0) {
            const float zv = (float)pz[(size_t)t * 8192];
            y += Dp * xv;
            const float g = zv / (1.f + __expf(-zv));
            py[(size_t)t * 4096] = (__bf16)(y * g);
        }
    }

    if (c == NC - 1) {
        *(float4*)&h_out[((size_t)b * 4096 + d) * 16 + sub * 4] =
            make_float4(h0, h1, h2, h3);
    }
}

// ===========================================================================
// Cooperative megakernel: all 8 stages, grid.sync() between them.
// 1024 blocks x 256 threads, 4 blocks/CU co-resident (launch_bounds 256,4;
// 32 KB LDS -> 128 KB/CU of 160).
// ===========================================================================
struct MegaArgs {
    const float *x, *wi, *wo, *wx, *wdt;
    const float *h_in, *conv_cache, *conv_w, *conv_b, *dt_proj_b, *A_log, *D_param;
    float *out, *h_out, *cc_out;
    __bf16 *xz16, *x16, *wi16, *wo16, *xs16, *ys16, *wx16, *wdt16, *delta16;
    float *dbc, *P, *S;
};

__global__ __launch_bounds__(256, 4) void mega(MegaArgs a)
{
    cooperative_groups::grid_group grid = cooperative_groups::this_grid();
    __shared__ __bf16 As[128 * 64];
    __shared__ __bf16 Bs[128 * 64];
    const int tid = threadIdx.x;
    const int bid = blockIdx.x;

    // 0) casts + zero-inits (grid-stride over 4997120 groups)
    for (size_t g = (size_t)bid * 256 + tid; g < 4997120; g += 262144)
        dev_cast(g, a.x, a.wi, a.wo, a.wx, a.wdt,
                 a.x16, a.wi16, a.wo16, a.wx16, a.wdt16,
                 (__bf16*)a.dbc, (__bf16*)a.out);
    grid.sync();

    // 1) in_proj: xz16 = x @ wi^T  (M=2048,N=8192,K=2048)
    dev_gemm<0, 64, __bf16>(a.x16, 2048, a.wi16, 2048, a.xz16, 8192,
                            2048, 8192, nullptr, bid & 63, bid >> 6, 0, As, Bs, tid);
    grid.sync();

    // 2) conv + silu -> xs16, cc_out
    dev_conv(a.xz16, a.conv_cache, a.conv_w, a.conv_b, a.xs16, a.cc_out, bid, tid);
    grid.sync();

    // 3) x_proj: dbc += xs @ wx^T  (split-K=16, 512 busy blocks)
    if (bid < 512)
        dev_gemm<2, 32, float>(a.xs16, 4096, a.wx16, 4096, a.dbc, 160,
                               256, 160, nullptr, bid & 1, (bid >> 1) & 15, bid >> 5,
                               As, Bs, tid);
    grid.sync();

    // 4) dt_proj -> delta16 (512 busy blocks)
    if (bid < 512)
        dev_dt(a.dbc, a.wdt16, a.delta16, a.dt_proj_b, bid & 31, bid >> 5, As, Bs, tid);
    grid.sync();

    // 5) scan phase A (2 slices/block)
    dev_scanA(bid * 256 + tid,          a.delta16, a.dbc, a.xs16, a.A_log, a.P, a.S);
    dev_scanA(bid * 256 + tid + 262144, a.delta16, a.dbc, a.xs16, a.A_log, a.P, a.S);
    grid.sync();

    // 6) scan phase C (2 slices/block)
    dev_scanC(bid * 256 + tid,          a.delta16, a.xz16, a.dbc, a.xs16, a.P, a.S,
              a.h_in, a.A_log, a.D_param, a.ys16, a.h_out);
    dev_scanC(bid * 256 + tid + 262144, a.delta16, a.xz16, a.dbc, a.xs16, a.P, a.S,
              a.h_in, a.A_log, a.D_param, a.ys16, a.h_out);
    grid.sync();

    // 7) out_proj: out += ys @ wo^T  (split-K=4, all blocks busy)
    dev_gemm<2, 64, float>(a.ys16, 4096, a.wo16, 4096, a.out, 2048,
                           1024, 2048, nullptr, bid & 15, (bid >> 4) & 15, bid >> 8,
                           As, Bs, tid);
}

// ===========================================================================
// Standalone fallback kernels (R7 path) built on the same device functions
// ===========================================================================
__global__ __launch_bounds__(256) void k_cast(
    const float* x, const float* wi, const float* wo, const float* wx,
    const float* wdt, __bf16* x16, __bf16* wi16, __bf16* wo16, __bf16* wx16,
    __bf16* wdt16, __bf16* dbc16, __bf16* out16)
{
    dev_cast((size_t)blockIdx.x * 256 + threadIdx.x,
             x, wi, wo, wx, wdt, x16, wi16, wo16, wx16, wdt16, dbc16, out16);
}

template <int EPI, int KSTEP, typename OutT>
__global__ __launch_bounds__(256) void k_gemm(
    const __bf16* A, int lda, const __bf16* W, int ldw,
    OutT* C, int ldc, int Kloop, int Nmax, const float* bias)
{
    __shared__ __bf16 As[128 * KSTEP];
    __shared__ __bf16 Bs[128 * KSTEP];
    dev_gemm<EPI, KSTEP, OutT>(A, lda, W, ldw, C, ldc, Kloop, Nmax, bias,
                               blockIdx.x, blockIdx.y, blockIdx.z, As, Bs, threadIdx.x);
}

__global__ __launch_bounds__(256) void k_dt(
    const float* A, const __bf16* W, __bf16* C, const float* bias)
{
    __shared__ __bf16 As[128 * 32];
    __shared__ __bf16 Bs[128 * 32];
    dev_dt(A, W, C, bias, blockIdx.x, blockIdx.y, As, Bs, threadIdx.x);
}

__global__ __launch_bounds__(256) void k_conv(
    const __bf16* xz16, const float* conv_cache, const float* conv_w,
    const float* conv_b, __bf16* xs16, float* cc_out)
{
    dev_conv(xz16, conv_cache, conv_w, conv_b, xs16, cc_out,
             blockIdx.x, threadIdx.x);
}

__global__ __launch_bounds__(256) void k_scanA(
    const __bf16* delta16, const float* dbc, const __bf16* xs16,
    const float* A_log, float* P, float* S)
{
    dev_scanA(blockIdx.x * 256 + threadIdx.x, delta16, dbc, xs16, A_log, P, S);
}

__global__ __launch_bounds__(256) void k_scanC(
    const __bf16* delta16, const __bf16* xz16, const float* dbc,
    const __bf16* xs16, const float* P, const float* S, const float* h_in,
    const float* A_log, const float* D_param, __bf16* ys16, float* h_out)
{
    dev_scanC(blockIdx.x * 256 + threadIdx.x, delta16, xz16, dbc, xs16, P, S,
              h_in, A_log, D_param, ys16, h_out);
}

// ===========================================================================
extern "C" void kernel_launch(void* const* d_in, const int* in_sizes, int n_in,
                              void* d_out, int out_size, void* d_ws, size_t ws_size,
                              hipStream_t stream)
{
    const float* x          = (const float*)d_in[0];
    const float* h_in       = (const float*)d_in[1];
    const float* conv_cache = (const float*)d_in[2];
    const float* in_proj_w  = (const float*)d_in[3];
    const float* conv_w     = (const float*)d_in[4];
    const float* conv_b     = (const float*)d_in[5];
    const float* x_proj_w   = (const float*)d_in[6];
    const float* dt_proj_w  = (const float*)d_in[7];
    const float* dt_proj_b  = (const float*)d_in[8];
    const float* A_log      = (const float*)d_in[9];
    const float* D_param    = (const float*)d_in[10];
    const float* out_proj_w = (const float*)d_in[11];

    float* out    = (float*)d_out;
    float* h_out  = (float*)d_out + (size_t)NB * TT * D_MODEL;
    float* cc_out = h_out + (size_t)NB * D_INNER * D_STATE;

    char* ws = (char*)d_ws;
    // [0,33.5M) xz16 | [33.5,41.9M) x16 -> Pbuf | [41.9,75.5M) wi16 ->
    //   delta16 [41.9,58.7M) + Sbuf [58.7,67.1M) | [75.5,92.3M) wo16 |
    // [92.3,109M) xs16 | [109,110.4M) dbc | [110.4,127.1M) ys16 |
    // [127.1,129.2M) wx16 | [129.2,130.3M) wdt16
    __bf16* xz16    = (__bf16*)(ws);
    __bf16* x16     = (__bf16*)(ws + 33554432);
    float*  Pbuf    = (float*)(ws + 33554432);
    __bf16* wi16    = (__bf16*)(ws + 41943040);
    __bf16* delta16 = (__bf16*)(ws + 41943040);
    float*  Sbuf    = (float*)(ws + 58720256);
    __bf16* wo16    = (__bf16*)(ws + 75497472);
    __bf16* xs16    = (__bf16*)(ws + 92274688);
    float*  dbc     = (float*)(ws + 109051904);
    __bf16* ys16    = (__bf16*)(ws + 110362624);
    __bf16* wx16    = (__bf16*)(ws + 127139840);
    __bf16* wdt16   = (__bf16*)(ws + 129236992);

    MegaArgs ma;
    ma.x = x; ma.wi = in_proj_w; ma.wo = out_proj_w; ma.wx = x_proj_w; ma.wdt = dt_proj_w;
    ma.h_in = h_in; ma.conv_cache = conv_cache; ma.conv_w = conv_w; ma.conv_b = conv_b;
    ma.dt_proj_b = dt_proj_b; ma.A_log = A_log; ma.D_param = D_param;
    ma.out = out; ma.h_out = h_out; ma.cc_out = cc_out;
    ma.xz16 = xz16; ma.x16 = x16; ma.wi16 = wi16; ma.wo16 = wo16; ma.xs16 = xs16;
    ma.ys16 = ys16; ma.wx16 = wx16; ma.wdt16 = wdt16; ma.delta16 = delta16;
    ma.dbc = dbc; ma.P = Pbuf; ma.S = Sbuf;

    void* kp[] = { (void*)&ma };
    hipError_t ce = hipLaunchCooperativeKernel(
        (const void*)mega, dim3(1024), dim3(256), kp, 0, stream);

    if (ce != hipSuccess) {
        (void)hipGetLastError();   // clear, run proven multi-launch path
        dim3 blk(256);
        k_cast<<<dim3(19520), blk, 0, stream>>>(
            x, in_proj_w, out_proj_w, x_proj_w, dt_proj_w,
            x16, wi16, wo16, wx16, wdt16, (__bf16*)dbc, (__bf16*)out);
        k_gemm<0, 64, __bf16><<<dim3(64, 16, 1), blk, 0, stream>>>(
            x16, 2048, wi16, 2048, xz16, 8192, 2048, 8192, nullptr);
        k_conv<<<dim3(1024), blk, 0, stream>>>(
            xz16, conv_cache, conv_w, conv_b, xs16, cc_out);
        k_gemm<2, 32, float><<<dim3(2, 16, 16), blk, 0, stream>>>(
            xs16, 4096, wx16, 4096, dbc, 160, 256, 160, nullptr);
        k_dt<<<dim3(32, 16), blk, 0, stream>>>(dbc, wdt16, delta16, dt_proj_b);
        k_scanA<<<dim3(2048), blk, 0, stream>>>(delta16, dbc, xs16, A_log, Pbuf, Sbuf);
        k_scanC<<<dim3(2048), blk, 0, stream>>>(
            delta16, xz16, dbc, xs16, Pbuf, Sbuf, h_in, A_log, D_param, ys16, h_out);
        k_gemm<2, 64, float><<<dim3(16, 16, 2), blk, 0, stream>>>(
            ys16, 4096, wo16, 4096, out, 2048, 2048, 2048, nullptr);
    }
}

// Round 9
// 498.561 us; speedup vs baseline: 2.7382x; 2.7382x over previous
//
#include <hip/hip_runtime.h>
#include <hip/hip_bf16.h>
#include <math.h>

#define D_MODEL 2048
#define D_INNER 4096
#define D_STATE 16
#define DT_RANK 128
#define NB      2
#define TT      1024
#define M_TOT   (NB * TT)
#define NC      16                 // scan chunks
#define CL      64                 // chunk length
#define CTC     32                 // conv t-chunk (1024 blocks)

typedef __bf16 bf16x8_t __attribute__((ext_vector_type(8)));
typedef float  f32x4_t  __attribute__((ext_vector_type(4)));

// ===========================================================================
// Device stage functions
// ===========================================================================

// ---- fused cast/zero.  g = 16-byte group index, total 4997120. ----
__device__ __forceinline__ void dev_cast(
    size_t g,
    const float* x,  const float* wi, const float* wo, const float* wx,
    const float* wdt,
    __bf16* x16, __bf16* wi16, __bf16* wo16, __bf16* wx16,
    __bf16* wdt16, __bf16* dbc16, __bf16* out16)
{
    const float* src; __bf16* dst; size_t off;
    if      (g < 524288)  { src = x;   dst = x16;   off = g; }
    else if (g < 2621440) { src = wi;  dst = wi16;  off = g - 524288; }
    else if (g < 3670016) { src = wo;  dst = wo16;  off = g - 2621440; }
    else if (g < 3801088) { off = g - 3670016; dst = wx16;
                            src = (g < 3751936) ? wx : nullptr; }
    else if (g < 3866624) { src = wdt; dst = wdt16; off = g - 3801088; }
    else if (g < 3948544) { src = nullptr; dst = dbc16; off = g - 3866624; }
    else                  { src = nullptr; dst = out16; off = g - 3948544; }

    bf16x8_t v;
    if (src) {
        const float4 f0 = ((const float4*)src)[2 * off];
        const float4 f1 = ((const float4*)src)[2 * off + 1];
        v[0] = (__bf16)f0.x; v[1] = (__bf16)f0.y; v[2] = (__bf16)f0.z; v[3] = (__bf16)f0.w;
        v[4] = (__bf16)f1.x; v[5] = (__bf16)f1.y; v[6] = (__bf16)f1.z; v[7] = (__bf16)f1.w;
    } else {
        v = (bf16x8_t)(__bf16)0.f;
    }
    ((bf16x8_t*)dst)[off] = v;
}

// ---- bf16 MFMA GEMM 128x128 tile, m97 structure ----
template <int EPI, int KSTEP, typename OutT>
__device__ __forceinline__ void dev_gemm(
    const __bf16* __restrict__ A, int lda,
    const __bf16* __restrict__ W, int ldw,
    OutT* __restrict__ C, int ldc,
    int Kloop, int Nmax, const float* __restrict__ bias,
    int bx, int by, int bz, __bf16* As, __bf16* Bs, int tid)
{
    const int wave = tid >> 6;
    const int lane = tid & 63;
    const int m0 = by * 128;
    const int n0 = bx * 128;
    const int mw = (wave >> 1) * 64;
    const int nw = (wave & 1) * 64;
    const int koff = bz * Kloop;

    f32x4_t acc[4][4] = {};

    const int g0 = wave * 2;
    const int rA = g0 * 16 + (lane >> 2);
    const int kk = (lane & 3) * 8;

    const __bf16* gA0 = A + (size_t)(m0 + rA) * lda + kk + koff;
    const __bf16* gA1 = gA0 + (size_t)16 * lda;
    const __bf16* gB0 = W + (size_t)(n0 + rA) * ldw + kk + koff;
    const __bf16* gB1 = gB0 + (size_t)16 * ldw;

    __bf16* lA0 = As + (size_t)g0 * 512;
    __bf16* lA1 = As + (size_t)(g0 + 1) * 512;
    __bf16* lB0 = Bs + (size_t)g0 * 512;
    __bf16* lB1 = Bs + (size_t)(g0 + 1) * 512;

    const int fr = lane & 15;
    const int fk = (lane >> 4) * 8;

    for (int k0 = 0; k0 < Kloop; k0 += KSTEP) {
#pragma unroll
        for (int p = 0; p < KSTEP / 32; p++) {
            const int kp = k0 + p * 32;
            const int lp = p * 4096;
            __builtin_amdgcn_global_load_lds(
                (const __attribute__((address_space(1))) void*)(gA0 + kp),
                (__attribute__((address_space(3))) void*)(lA0 + lp), 16, 0, 0);
            __builtin_amdgcn_global_load_lds(
                (const __attribute__((address_space(1))) void*)(gA1 + kp),
                (__attribute__((address_space(3))) void*)(lA1 + lp), 16, 0, 0);
            __builtin_amdgcn_global_load_lds(
                (const __attribute__((address_space(1))) void*)(gB0 + kp),
                (__attribute__((address_space(3))) void*)(lB0 + lp), 16, 0, 0);
            __builtin_amdgcn_global_load_lds(
                (const __attribute__((address_space(1))) void*)(gB1 + kp),
                (__attribute__((address_space(3))) void*)(lB1 + lp), 16, 0, 0);
        }
        __syncthreads();

#pragma unroll
        for (int p = 0; p < KSTEP / 32; p++) {
            const int lp = p * 4096;
            bf16x8_t av[4], bv[4];
#pragma unroll
            for (int mt = 0; mt < 4; mt++)
                av[mt] = *(const bf16x8_t*)&As[lp + (mw + mt * 16 + fr) * 32 + fk];
#pragma unroll
            for (int nt = 0; nt < 4; nt++)
                bv[nt] = *(const bf16x8_t*)&Bs[lp + (nw + nt * 16 + fr) * 32 + fk];

#pragma unroll
            for (int mt = 0; mt < 4; mt++)
#pragma unroll
                for (int nt = 0; nt < 4; nt++)
                    acc[mt][nt] = __builtin_amdgcn_mfma_f32_16x16x32_bf16(
                        av[mt], bv[nt], acc[mt][nt], 0, 0, 0);
        }
        __syncthreads();
    }

    // C/D layout: col = lane&15, row = (lane>>4)*4 + reg
    const int cn = n0 + nw + (lane & 15);
    const int rb = m0 + mw + (lane >> 4) * 4;
#pragma unroll
    for (int mt = 0; mt < 4; mt++)
#pragma unroll
        for (int nt = 0; nt < 4; nt++) {
            const int n = cn + nt * 16;
            if (n >= Nmax) continue;
#pragma unroll
            for (int r = 0; r < 4; r++) {
                float v = acc[mt][nt][r];
                OutT* p = &C[(size_t)(rb + mt * 16 + r) * ldc + n];
                if (EPI == 1) {
                    v += bias[n];
                    v = (v > 20.f) ? v : log1pf(__expf(v));
                    *p = (OutT)v;
                } else if (EPI == 2) {
                    atomicAdd((float*)p, v);
                } else {
                    *p = (OutT)v;
                }
            }
        }
}

// ---- dt_proj GEMM with inlined fp32->bf16 A staging ----
__device__ __forceinline__ void dev_dt(
    const float* __restrict__ A,      // dbc (ld 160)
    const __bf16* __restrict__ W,     // wdt16 (4096,128)
    __bf16* __restrict__ C,           // delta16 (ld 4096)
    const float* __restrict__ bias,
    int bx, int by, __bf16* As, __bf16* Bs, int tid)
{
    const int wave = tid >> 6;
    const int lane = tid & 63;
    const int m0 = by * 128;
    const int n0 = bx * 128;
    const int mw = (wave >> 1) * 64;
    const int nw = (wave & 1) * 64;

    f32x4_t acc[4][4] = {};

    const int g0 = wave * 2;
    const int rA = g0 * 16 + (lane >> 2);
    const int kk = (lane & 3) * 8;

    const float*  gA0 = A + (size_t)(m0 + rA) * 160 + kk;
    const float*  gA1 = gA0 + (size_t)16 * 160;
    const __bf16* gB0 = W + (size_t)(n0 + rA) * 128 + kk;
    const __bf16* gB1 = gB0 + (size_t)16 * 128;

    __bf16* lA0 = As + (size_t)g0 * 512;
    __bf16* lA1 = As + (size_t)(g0 + 1) * 512;
    __bf16* lB0 = Bs + (size_t)g0 * 512;
    __bf16* lB1 = Bs + (size_t)(g0 + 1) * 512;

    const int fr = lane & 15;
    const int fk = (lane >> 4) * 8;

    for (int k0 = 0; k0 < 128; k0 += 32) {
        const float4 a0 = *(const float4*)(gA0 + k0);
        const float4 a1 = *(const float4*)(gA0 + k0 + 4);
        const float4 a2 = *(const float4*)(gA1 + k0);
        const float4 a3 = *(const float4*)(gA1 + k0 + 4);
        bf16x8_t va, vb;
        va[0] = (__bf16)a0.x; va[1] = (__bf16)a0.y; va[2] = (__bf16)a0.z; va[3] = (__bf16)a0.w;
        va[4] = (__bf16)a1.x; va[5] = (__bf16)a1.y; va[6] = (__bf16)a1.z; va[7] = (__bf16)a1.w;
        vb[0] = (__bf16)a2.x; vb[1] = (__bf16)a2.y; vb[2] = (__bf16)a2.z; vb[3] = (__bf16)a2.w;
        vb[4] = (__bf16)a3.x; vb[5] = (__bf16)a3.y; vb[6] = (__bf16)a3.z; vb[7] = (__bf16)a3.w;
        ((bf16x8_t*)lA0)[lane] = va;
        ((bf16x8_t*)lA1)[lane] = vb;
        __builtin_amdgcn_global_load_lds(
            (const __attribute__((address_space(1))) void*)(gB0 + k0),
            (__attribute__((address_space(3))) void*)lB0, 16, 0, 0);
        __builtin_amdgcn_global_load_lds(
            (const __attribute__((address_space(1))) void*)(gB1 + k0),
            (__attribute__((address_space(3))) void*)lB1, 16, 0, 0);
        __syncthreads();

        bf16x8_t av[4], bv[4];
#pragma unroll
        for (int mt = 0; mt < 4; mt++)
            av[mt] = *(const bf16x8_t*)&As[(mw + mt * 16 + fr) * 32 + fk];
#pragma unroll
        for (int nt = 0; nt < 4; nt++)
            bv[nt] = *(const bf16x8_t*)&Bs[(nw + nt * 16 + fr) * 32 + fk];

#pragma unroll
        for (int mt = 0; mt < 4; mt++)
#pragma unroll
            for (int nt = 0; nt < 4; nt++)
                acc[mt][nt] = __builtin_amdgcn_mfma_f32_16x16x32_bf16(
                    av[mt], bv[nt], acc[mt][nt], 0, 0, 0);
        __syncthreads();
    }

    const int cn = n0 + nw + (lane & 15);
    const int rb = m0 + mw + (lane >> 4) * 4;
#pragma unroll
    for (int mt = 0; mt < 4; mt++)
#pragma unroll
        for (int nt = 0; nt < 4; nt++) {
            const int n = cn + nt * 16;
            const float bs = bias[n];
#pragma unroll
            for (int r = 0; r < 4; r++) {
                float v = acc[mt][nt][r] + bs;
                v = (v > 20.f) ? v : log1pf(__expf(v));
                C[(size_t)(rb + mt * 16 + r) * 4096 + n] = (__bf16)v;
            }
        }
}

// ---- causal depthwise conv(4) + bias + silu; 1024 blocks, CTC=32 ----
__device__ __forceinline__ void dev_conv(
    const __bf16* __restrict__ xz16,
    const float* __restrict__ conv_cache,
    const float* __restrict__ conv_w,
    const float* __restrict__ conv_b,
    __bf16* __restrict__ xs16,
    float* __restrict__ cc_out, int bid, int tid)
{
    const int t0 = (bid & 31) * CTC;
    const int d  = (((bid >> 5) & 15) << 8) + tid;
    const int b  = bid >> 9;

    const float4 w  = *(const float4*)&conv_w[d * 4];
    const float bias = conv_b[d];

    float v[CTC + 3];
    if (t0 == 0) {
        v[0] = conv_cache[(b * D_INNER + d) * 3 + 0];
        v[1] = conv_cache[(b * D_INNER + d) * 3 + 1];
        v[2] = conv_cache[(b * D_INNER + d) * 3 + 2];
    } else {
        v[0] = (float)xz16[(size_t)(b * TT + t0 - 3) * 8192 + d];
        v[1] = (float)xz16[(size_t)(b * TT + t0 - 2) * 8192 + d];
        v[2] = (float)xz16[(size_t)(b * TT + t0 - 1) * 8192 + d];
    }
#pragma unroll
    for (int k = 0; k < CTC; k++)
        v[k + 3] = (float)xz16[(size_t)(b * TT + t0 + k) * 8192 + d];

#pragma unroll
    for (int k = 0; k < CTC; k++) {
        float c = v[k] * w.x + v[k + 1] * w.y + v[k + 2] * w.z + v[k + 3] * w.w + bias;
        float s = c / (1.f + __expf(-c));
        xs16[(size_t)(b * TT + t0 + k) * 4096 + d] = (__bf16)s;
    }

    if (t0 + CTC == TT) {
        cc_out[(b * D_INNER + d) * 3 + 0] = v[CTC];
        cc_out[(b * D_INNER + d) * 3 + 1] = v[CTC + 1];
        cc_out[(b * D_INNER + d) * 3 + 2] = v[CTC + 2];
    }
}

// ---- scan phase A (per-chunk local scan + decay) ----
__device__ __forceinline__ void dev_scanA(
    int idx,
    const __bf16* __restrict__ delta16,
    const float* __restrict__ dbc,
    const __bf16* __restrict__ xs16,
    const float* __restrict__ A_log,
    float* __restrict__ P, float* __restrict__ S)
{
    const int sub = idx & 3;
    const int d   = (idx >> 2) & 4095;
    const int c   = (idx >> 14) & (NC - 1);
    const int b   = idx >> 18;

    const float4 Af = *(const float4*)&A_log[d * 16 + sub * 4];
    const float Ad0 = -__expf(Af.x), Ad1 = -__expf(Af.y);
    const float Ad2 = -__expf(Af.z), Ad3 = -__expf(Af.w);

    const int t0 = c * CL;
    const __bf16* pdelta = delta16 + (size_t)(b * TT + t0) * 4096 + d;
    const __bf16* px     = xs16 + (size_t)(b * TT + t0) * 4096 + d;
    const float*  pB     = dbc + ((size_t)b * TT + t0) * 160 + 128 + sub * 4;

    float h0 = 0.f, h1 = 0.f, h2 = 0.f, h3 = 0.f, sd = 0.f;
#pragma unroll 4
    for (int t = 0; t < CL; t++) {
        const float delta = (float)pdelta[(size_t)t * 4096];
        const float xv    = (float)px[(size_t)t * 4096];
        const float4 Bv   = *(const float4*)&pB[(size_t)t * 160];
        const float dx = delta * xv;
        h0 = __expf(delta * Ad0) * h0 + dx * Bv.x;
        h1 = __expf(delta * Ad1) * h1 + dx * Bv.y;
        h2 = __expf(delta * Ad2) * h2 + dx * Bv.z;
        h3 = __expf(delta * Ad3) * h3 + dx * Bv.w;
        sd += delta;
    }
    const size_t o = ((size_t)(b * NC + c) * 4096 + d) * 16 + sub * 4;
    *(float4*)&P[o] = make_float4(__expf(Ad0 * sd), __expf(Ad1 * sd),
                                  __expf(Ad2 * sd), __expf(Ad3 * sd));
    *(float4*)&S[o] = make_float4(h0, h1, h2, h3);
}

// ---- scan phase C (combine + re-scan, emit gated y, h_out) ----
__device__ __forceinline__ void dev_scanC(
    int idx,
    const __bf16* __restrict__ delta16,
    const __bf16* __restrict__ xz16,
    const float* __restrict__ dbc,
    const __bf16* __restrict__ xs16,
    const float* __restrict__ P, const float* __restrict__ S,
    const float* __restrict__ h_in,
    const float* __restrict__ A_log,
    const float* __restrict__ D_param,
    __bf16* __restrict__ ys16, float* __restrict__ h_out)
{
    const int sub = idx & 3;
    const int d   = (idx >> 2) & 4095;
    const int c   = (idx >> 14) & (NC - 1);   // wave-uniform
    const int b   = idx >> 18;

    const float4 Af = *(const float4*)&A_log[d * 16 + sub * 4];
    const float Ad0 = -__expf(Af.x), Ad1 = -__expf(Af.y);
    const float Ad2 = -__expf(Af.z), Ad3 = -__expf(Af.w);
    const float Dp = D_param[d];

    float4 hf = *(const float4*)&h_in[((size_t)b * 4096 + d) * 16 + sub * 4];
    float h0 = hf.x, h1 = hf.y, h2 = hf.z, h3 = hf.w;
    for (int cc = 0; cc < c; cc++) {
        const size_t o2 = ((size_t)(b * NC + cc) * 4096 + d) * 16 + sub * 4;
        const float4 p = *(const float4*)&P[o2];
        const float4 s = *(const float4*)&S[o2];
        h0 = p.x * h0 + s.x;
        h1 = p.y * h1 + s.y;
        h2 = p.z * h2 + s.z;
        h3 = p.w * h3 + s.w;
    }

    const int t0 = c * CL;
    const __bf16* pdelta = delta16 + (size_t)(b * TT + t0) * 4096 + d;
    const __bf16* pz     = xz16 + (size_t)(b * TT + t0) * 8192 + 4096 + d;
    const __bf16* px     = xs16 + (size_t)(b * TT + t0) * 4096 + d;
    const float*  pB     = dbc + ((size_t)b * TT + t0) * 160 + 128 + sub * 4;
    const float*  pC     = pB + 16;
    __bf16* py = ys16 + (size_t)(b * TT + t0) * 4096 + d;

#pragma unroll 4
    for (int t = 0; t < CL; t++) {
        const float delta = (float)pdelta[(size_t)t * 4096];
        const float xv    = (float)px[(size_t)t * 4096];
        const float4 Bv   = *(const float4*)&pB[(size_t)t * 160];
        const float4 Cv   = *(const float4*)&pC[(size_t)t * 160];
        const float dx = delta * xv;

        h0 = __expf(delta * Ad0) * h0 + dx * Bv.x;
        h1 = __expf(delta * Ad1) * h1 + dx * Bv.y;
        h2 = __expf(delta * Ad2) * h2 + dx * Bv.z;
        h3 = __expf(delta * Ad3) * h3 + dx * Bv.w;

        float y = h0 * Cv.x + h1 * Cv.y + h2 * Cv.z + h3 * Cv.w;
        y += __shfl_xor(y, 1);
        y += __shfl_xor(y, 2);

        if (sub == 0) {
            const float zv = (float)pz[(size_t)t * 8192];
            y += Dp * xv;
            const float g = zv / (1.f + __expf(-zv));
            py[(size_t)t * 4096] = (__bf16)(y * g);
        }
    }

    if (c == NC - 1) {
        *(float4*)&h_out[((size_t)b * 4096 + d) * 16 + sub * 4] =
            make_float4(h0, h1, h2, h3);
    }
}

// ===========================================================================
// Standalone kernels (proven R7 path)
// ===========================================================================
__global__ __launch_bounds__(256) void k_cast(
    const float* x, const float* wi, const float* wo, const float* wx,
    const float* wdt, __bf16* x16, __bf16* wi16, __bf16* wo16, __bf16* wx16,
    __bf16* wdt16, __bf16* dbc16, __bf16* out16)
{
    dev_cast((size_t)blockIdx.x * 256 + threadIdx.x,
             x, wi, wo, wx, wdt, x16, wi16, wo16, wx16, wdt16, dbc16, out16);
}

template <int EPI, int KSTEP, typename OutT>
__global__ __launch_bounds__(256) void k_gemm(
    const __bf16* A, int lda, const __bf16* W, int ldw,
    OutT* C, int ldc, int Kloop, int Nmax, const float* bias)
{
    __shared__ __bf16 As[128 * KSTEP];
    __shared__ __bf16 Bs[128 * KSTEP];
    dev_gemm<EPI, KSTEP, OutT>(A, lda, W, ldw, C, ldc, Kloop, Nmax, bias,
                               blockIdx.x, blockIdx.y, blockIdx.z, As, Bs, threadIdx.x);
}

__global__ __launch_bounds__(256) void k_dt(
    const float* A, const __bf16* W, __bf16* C, const float* bias)
{
    __shared__ __bf16 As[128 * 32];
    __shared__ __bf16 Bs[128 * 32];
    dev_dt(A, W, C, bias, blockIdx.x, blockIdx.y, As, Bs, threadIdx.x);
}

__global__ __launch_bounds__(256) void k_conv(
    const __bf16* xz16, const float* conv_cache, const float* conv_w,
    const float* conv_b, __bf16* xs16, float* cc_out)
{
    dev_conv(xz16, conv_cache, conv_w, conv_b, xs16, cc_out,
             blockIdx.x, threadIdx.x);
}

__global__ __launch_bounds__(256) void k_scanA(
    const __bf16* delta16, const float* dbc, const __bf16* xs16,
    const float* A_log, float* P, float* S)
{
    dev_scanA(blockIdx.x * 256 + threadIdx.x, delta16, dbc, xs16, A_log, P, S);
}

__global__ __launch_bounds__(256) void k_scanC(
    const __bf16* delta16, const __bf16* xz16, const float* dbc,
    const __bf16* xs16, const float* P, const float* S, const float* h_in,
    const float* A_log, const float* D_param, __bf16* ys16, float* h_out)
{
    dev_scanC(blockIdx.x * 256 + threadIdx.x, delta16, xz16, dbc, xs16, P, S,
              h_in, A_log, D_param, ys16, h_out);
}

// ===========================================================================
extern "C" void kernel_launch(void* const* d_in, const int* in_sizes, int n_in,
                              void* d_out, int out_size, void* d_ws, size_t ws_size,
                              hipStream_t stream)
{
    const float* x          = (const float*)d_in[0];
    const float* h_in       = (const float*)d_in[1];
    const float* conv_cache = (const float*)d_in[2];
    const float* in_proj_w  = (const float*)d_in[3];
    const float* conv_w     = (const float*)d_in[4];
    const float* conv_b     = (const float*)d_in[5];
    const float* x_proj_w   = (const float*)d_in[6];
    const float* dt_proj_w  = (const float*)d_in[7];
    const float* dt_proj_b  = (const float*)d_in[8];
    const float* A_log      = (const float*)d_in[9];
    const float* D_param    = (const float*)d_in[10];
    const float* out_proj_w = (const float*)d_in[11];

    float* out    = (float*)d_out;
    float* h_out  = (float*)d_out + (size_t)NB * TT * D_MODEL;
    float* cc_out = h_out + (size_t)NB * D_INNER * D_STATE;

    char* ws = (char*)d_ws;
    // [0,33.5M) xz16 | [33.5,41.9M) x16 -> Pbuf | [41.9,75.5M) wi16 ->
    //   delta16 [41.9,58.7M) + Sbuf [58.7,67.1M) | [75.5,92.3M) wo16 |
    // [92.3,109M) xs16 | [109,110.4M) dbc | [110.4,127.1M) ys16 |
    // [127.1,129.2M) wx16 | [129.2,130.3M) wdt16
    __bf16* xz16    = (__bf16*)(ws);
    __bf16* x16     = (__bf16*)(ws + 33554432);
    float*  Pbuf    = (float*)(ws + 33554432);
    __bf16* wi16    = (__bf16*)(ws + 41943040);
    __bf16* delta16 = (__bf16*)(ws + 41943040);
    float*  Sbuf    = (float*)(ws + 58720256);
    __bf16* wo16    = (__bf16*)(ws + 75497472);
    __bf16* xs16    = (__bf16*)(ws + 92274688);
    float*  dbc     = (float*)(ws + 109051904);
    __bf16* ys16    = (__bf16*)(ws + 110362624);
    __bf16* wx16    = (__bf16*)(ws + 127139840);
    __bf16* wdt16   = (__bf16*)(ws + 129236992);

    dim3 blk(256);

    // 0) all casts + all zero-inits (wx pad, dbc, out) in one dispatch
    k_cast<<<dim3(19520), blk, 0, stream>>>(
        x, in_proj_w, out_proj_w, x_proj_w, dt_proj_w,
        x16, wi16, wo16, wx16, wdt16, (__bf16*)dbc, (__bf16*)out);

    // 1) in_proj: xz16 = x @ wi^T  (M=2048, N=8192, K=2048; KSTEP=64)
    k_gemm<0, 64, __bf16><<<dim3(64, 16, 1), blk, 0, stream>>>(
        x16, 2048, wi16, 2048, xz16, 8192, 2048, 8192, nullptr);

    // 2) conv + silu -> xs16, new_conv_cache
    k_conv<<<dim3(1024), blk, 0, stream>>>(
        xz16, conv_cache, conv_w, conv_b, xs16, cc_out);

    // 3) x_proj: dbc += xs @ wx^T  (split-K=16, atomic; N=160 guarded)
    k_gemm<2, 32, float><<<dim3(2, 16, 16), blk, 0, stream>>>(
        xs16, 4096, wx16, 4096, dbc, 160, 256, 160, nullptr);

    // 4) dt_proj -> delta16 (inlined fp32 A cast + softplus + bf16 store)
    k_dt<<<dim3(32, 16), blk, 0, stream>>>(dbc, wdt16, delta16, dt_proj_b);

    // 5) chunked selective scan (2 phases) -> ys16 + h_out
    k_scanA<<<dim3(2048), blk, 0, stream>>>(delta16, dbc, xs16, A_log, Pbuf, Sbuf);
    k_scanC<<<dim3(2048), blk, 0, stream>>>(
        delta16, xz16, dbc, xs16, Pbuf, Sbuf, h_in, A_log, D_param, ys16, h_out);

    // 6) out_proj: out += ys @ wo^T  (split-K=4: 1024 blocks, 4/CU, 16 iters)
    k_gemm<2, 64, float><<<dim3(16, 16, 4), blk, 0, stream>>>(
        ys16, 4096, wo16, 4096, out, 2048, 1024, 2048, nullptr);
}